// Round 1
// 422.233 us; speedup vs baseline: 1.0000x; 1.0000x over previous
//
#include <hip/hip_runtime.h>
#include <cstdint>
#include <cstddef>

// Problem constants
#define M_DIM 8192
#define N_DIM 4096
#define K_DIM 4096

#define BM 128
#define BN 128
#define BK 64   // int8 elements per K-step (64 bytes per LDS row)

using i32x4 = __attribute__((ext_vector_type(4))) int;

__device__ __forceinline__ void async_load16(const void* g, void* l) {
    __builtin_amdgcn_global_load_lds(
        (const __attribute__((address_space(1))) void*)g,
        (__attribute__((address_space(3))) void*)l,
        16, 0, 0);
}

// Pack int32 values (range [-128,127]) to int8.
// Coalesced: lane l reads int4 at [base + l + 256*j] (16B/lane contiguous per
// instruction), writes one packed int at the same linear index (4B/lane
// contiguous). 4 independent loads in flight per thread.
// Each block covers 1024 int4s (16 KiB in, 4 KiB out).
__global__ __launch_bounds__(256) void pack_i8_kernel(const int4* __restrict__ src,
                                                      int* __restrict__ dst) {
    const long base = (long)blockIdx.x * 1024 + threadIdx.x;
#pragma unroll
    for (int j = 0; j < 4; ++j) {
        const long i = base + 256 * j;
        const int4 v = src[i];
        dst[i] = (v.x & 0xff) | ((v.y & 0xff) << 8) | ((v.z & 0xff) << 16) | (v.w << 24);
    }
}

// C[m][n] = sum_k A[m][k]*B[n][k]  (both K-contiguous, int8), then
// out = clamp(round((acc + bias[n]) * (0.05*wscale[n]/0.1)), -128, 127) as int32.
__global__ __launch_bounds__(256) void qgemm_i8_kernel(const int8_t* __restrict__ A,
                                                       const int8_t* __restrict__ B,
                                                       const int* __restrict__ bias,
                                                       const float* __restrict__ wscale,
                                                       int* __restrict__ C) {
    __shared__ int8_t As[BM * BK];   // 8 KiB, row-major 128 x 64B
    __shared__ int8_t Bs[BN * BK];   // 8 KiB

    const int tid  = threadIdx.x;
    const int wave = tid >> 6;
    const int lane = tid & 63;
    const int bm = blockIdx.y;
    const int bn = blockIdx.x;

    const int8_t* Ab = A + (size_t)bm * BM * K_DIM;
    const int8_t* Bb = B + (size_t)bn * BN * K_DIM;

    const int wm = wave >> 1;   // 0..1 : row half of tile
    const int wn = wave & 1;    // 0..1 : col half of tile

    i32x4 acc[4][4] = {};

    // staging geometry: each wave-issue covers 16 rows x 64B = 1 KiB linear LDS
    const int srow = lane >> 2;          // 0..15
    const int scol = (lane & 3) * 16;    // 0/16/32/48

    // fragment geometry
    const int kq   = (lane >> 4) * 16;       // byte offset in 64B row
    const int mrow = wm * 64 + (lane & 15);
    const int nrow = wn * 64 + (lane & 15);

    for (int kt = 0; kt < K_DIM; kt += BK) {
#pragma unroll
        for (int c = 0; c < 2; ++c) {
            const int rbase = (c * 4 + wave) * 16;
            async_load16(Ab + (size_t)(rbase + srow) * K_DIM + kt + scol,
                         &As[(c * 4 + wave) * 1024]);
            async_load16(Bb + (size_t)(rbase + srow) * K_DIM + kt + scol,
                         &Bs[(c * 4 + wave) * 1024]);
        }
        __syncthreads();

        i32x4 af[4], bf[4];
#pragma unroll
        for (int i = 0; i < 4; ++i)
            af[i] = *(const i32x4*)&As[(mrow + i * 16) * BK + kq];
#pragma unroll
        for (int j = 0; j < 4; ++j)
            bf[j] = *(const i32x4*)&Bs[(nrow + j * 16) * BK + kq];

#pragma unroll
        for (int i = 0; i < 4; ++i)
#pragma unroll
            for (int j = 0; j < 4; ++j)
                acc[i][j] = __builtin_amdgcn_mfma_i32_16x16x64_i8(af[i], bf[j], acc[i][j], 0, 0, 0);

        __syncthreads();
    }

    // Epilogue. C/D layout: col = lane&15, row = (lane>>4)*4 + reg
    const int col16 = lane & 15;
    const int rquad = (lane >> 4) * 4;
#pragma unroll
    for (int j = 0; j < 4; ++j) {
        const int col = bn * BN + wn * 64 + j * 16 + col16;
        // match np ref arithmetic exactly: (0.05f * ws) / 0.1f, all f32
        float s = 0.05f * wscale[col];
        s = s / 0.1f;
        const float bz = (float)bias[col];
#pragma unroll
        for (int i = 0; i < 4; ++i) {
            const int row0 = bm * BM + wm * 64 + i * 16 + rquad;
#pragma unroll
            for (int r = 0; r < 4; ++r) {
                float v = ((float)acc[i][j][r] + bz) * s;
                v = rintf(v);                          // RTNE, matches np.round
                v = fminf(fmaxf(v, -128.0f), 127.0f);
                C[(size_t)(row0 + r) * N_DIM + col] = (int)v;
            }
        }
    }
}

extern "C" void kernel_launch(void* const* d_in, const int* in_sizes, int n_in,
                              void* d_out, int out_size, void* d_ws, size_t ws_size,
                              hipStream_t stream) {
    const int*   x32    = (const int*)d_in[0];     // int8 values promoted to int32
    const int*   w32    = (const int*)d_in[1];
    const int*   bias   = (const int*)d_in[2];
    const float* wscale = (const float*)d_in[3];
    int*         out    = (int*)d_out;

    int8_t* xp = (int8_t*)d_ws;                         // 32 MiB packed x
    int8_t* wp = xp + (size_t)M_DIM * K_DIM;            // 16 MiB packed w

    {
        // 8192*4096 int32 values = 8.39M int4s; 1024 int4s per block
        const int blocks = (int)((long)M_DIM * K_DIM / 4 / 1024);
        pack_i8_kernel<<<blocks, 256, 0, stream>>>((const int4*)x32, (int*)xp);
    }
    {
        const int blocks = (int)((long)N_DIM * K_DIM / 4 / 1024);
        pack_i8_kernel<<<blocks, 256, 0, stream>>>((const int4*)w32, (int*)wp);
    }

    dim3 grid(N_DIM / BN, M_DIM / BM);   // (32, 64)
    qgemm_i8_kernel<<<grid, 256, 0, stream>>>(xp, wp, bias, wscale, out);
}